// Round 1
// baseline (627.461 us; speedup 1.0000x reference)
//
#include <hip/hip_runtime.h>
#include <hip/hip_fp16.h>

// WindowAttention fused kernel for MI355X (gfx950).
// B=4096 windows, N=49 tokens (pad 64), C=192, H=6, hd=32.
// V2: swapped-operand attention (S^T = K Q^T, O^T = V^T P^T) keeps softmax and
// P/O lane-local -> Pb/Ob/maskS LDS eliminated, LDS 62976 -> 40448 B,
// 2 -> 4 blocks/CU. Bias+mask precombined into one fp16 table in prep.

typedef short bf16x8 __attribute__((ext_vector_type(8)));
typedef float f32x4 __attribute__((ext_vector_type(4)));

#define MFMA16(a, b, c) __builtin_amdgcn_mfma_f32_16x16x32_bf16((a), (b), (c), 0, 0, 0)

#define DIMC 192
#define NTOK 49

// round-to-nearest-even fp32 -> bf16
__device__ __forceinline__ unsigned short f2bf(float f) {
  unsigned int u = __float_as_uint(f);
  u += 0x7fffu + ((u >> 16) & 1u);
  return (unsigned short)(u >> 16);
}

// packed fp32x2 -> bf16x2 (RNE), single VALU op
__device__ __forceinline__ unsigned int cvt_pk_bf16(float lo, float hi) {
  unsigned int r;
  asm("v_cvt_pk_bf16_f32 %0, %1, %2" : "=v"(r) : "v"(lo), "v"(hi));
  return r;
}

// prep: bf16 weights + combined (bias+mask) fp16 table, fragment-permuted:
// bm[widx][h] tile of 4096 halfs, offset = ((nt*4 + lq)*64 + q)*4 + r,
// value = bias[h][q][k] + mask[widx][q][k], k = nt*16 + lq*4 + r.
// k >= 49 -> -30000 (masked keys), q >= 49 -> 0 (rows discarded).
__global__ void prep_kernel(const float* __restrict__ qkv_w,
                            const float* __restrict__ proj_w,
                            const float* __restrict__ bias_table,
                            const int* __restrict__ rel_idx,
                            const float* __restrict__ mask,
                            unsigned short* __restrict__ qkv_wb,
                            unsigned short* __restrict__ proj_wb,
                            __half* __restrict__ bmT) {
  int i = blockIdx.x * 256 + threadIdx.x;
  if (i < 576 * 192) qkv_wb[i] = f2bf(qkv_w[i]);
  if (i < 192 * 192) proj_wb[i] = f2bf(proj_w[i]);
  // bm: i in [0, 64*6*4096)
  {
    int r = i & 3;
    int q = (i >> 2) & 63;
    int lq = (i >> 8) & 3;
    int nt = (i >> 10) & 3;
    int hw = i >> 12;          // widx*6 + h
    int h = hw % 6;
    int widx = hw / 6;
    int k = nt * 16 + lq * 4 + r;
    float v;
    if (k >= NTOK) v = -30000.f;
    else if (q >= NTOK) v = 0.f;
    else v = bias_table[rel_idx[q * NTOK + k] * 6 + h] +
             mask[(size_t)widx * (NTOK * NTOK) + q * NTOK + k];
    bmT[i] = __float2half(v);
  }
}

__global__ __launch_bounds__(256, 4) void winattn_kernel(
    const float* __restrict__ x,
    const float* __restrict__ qkv_b,
    const float* __restrict__ proj_b,
    const unsigned short* __restrict__ qkv_wb,
    const unsigned short* __restrict__ proj_wb,
    const __half* __restrict__ bmT,
    float* __restrict__ out) {
  // LDS: 40,448 B total -> 4 blocks/CU (160 KiB/CU)
  __shared__ unsigned short xb[64 * 200];   // x in bf16, row stride 200
  __shared__ unsigned short Qs[64 * 40];    // per-head Q (scaled), [token][d]
  __shared__ unsigned short Ks[64 * 40];    // per-head K, [token][d]
  __shared__ unsigned short Vts[32 * 72];   // per-head V^T [d][token], stride 72

  const int tid = threadIdx.x;
  const int b = blockIdx.x;
  const int widx = b & 63;
  const int lane = tid & 63;
  const int wv = tid >> 6;          // wave 0..3
  const int lq = lane >> 4;         // quad 0..3
  const int ln = lane & 15;

  // ---------------- stage x (bf16, zero rows >= 49)
  {
    const float4* xp = (const float4*)(x + (size_t)b * (NTOK * DIMC));
    for (int i = tid; i < NTOK * DIMC / 4; i += 256) {
      float4 v = xp[i];
      int fl = i * 4;
      int r = fl / DIMC;
      int c = fl - r * DIMC;
      unsigned int lo = (unsigned int)f2bf(v.x) | ((unsigned int)f2bf(v.y) << 16);
      unsigned int hi = (unsigned int)f2bf(v.z) | ((unsigned int)f2bf(v.w) << 16);
      *(uint2*)(&xb[r * 200 + c]) = make_uint2(lo, hi);
    }
    for (int i = tid; i < 15 * 200 / 2; i += 256)
      ((unsigned int*)(&xb[49 * 200]))[i] = 0u;
  }

  // persistent proj accumulators: wave owns q-rows [wv*16, wv*16+16), all 192 cols
  f32x4 pacc[12];
#pragma unroll
  for (int nti = 0; nti < 12; ++nti) {
    float pbv = proj_b[nti * 16 + ln];
    pacc[nti] = (f32x4){pbv, pbv, pbv, pbv};
  }
  __syncthreads();

  const float scale = 0.17677669529663687f;  // 1/sqrt(32)
  const __half* bmp = bmT + (size_t)widx * 6 * 4096;
  // cross-lq redistribution source lanes (same ln, lq_s = (lq&1)*2 + {0,1})
  const int sA = ((lq & 1) << 5) | ln;
  const int sB = sA + 16;
  const int hiSel = lq >> 1;

  for (int h = 0; h < 6; ++h) {
    // bias+mask fragment loads for this head (issued early; complete by the
    // vmcnt drain at the post-QKV barrier). Lane covers k = nt*16+lq*4+{0..3},
    // q = wv*16+ln.
    uint2 bmu[4];
    {
      const __half* bmh = bmp + (size_t)h * 4096;
#pragma unroll
      for (int nt = 0; nt < 4; ++nt)
        bmu[nt] = *(const uint2*)(bmh + ((nt * 4 + lq) * 64 + wv * 16 + ln) * 4);
    }

    // ---------------- per-head QKV GEMM: 24 tiles / 4 waves = 6 each (3 duos)
    for (int tt = 0; tt < 6; tt += 2) {
      int t0 = wv * 6 + tt;
      int t1 = t0 + 1;
      int nt0 = t0 >> 2, mt0 = t0 & 3;
      int nt1 = t1 >> 2, mt1 = t1 & 3;
      int oc0 = (nt0 >> 1) * DIMC + h * 32 + (nt0 & 1) * 16 + ln;
      int oc1 = (nt1 >> 1) * DIMC + h * 32 + (nt1 & 1) * 16 + ln;
      const unsigned short* w0p = qkv_wb + (size_t)oc0 * DIMC + lq * 8;
      const unsigned short* w1p = qkv_wb + (size_t)oc1 * DIMC + lq * 8;
      bf16x8 w0[6], w1[6];
#pragma unroll
      for (int ks = 0; ks < 6; ++ks) {
        w0[ks] = *(const bf16x8*)(w0p + ks * 32);
        w1[ks] = *(const bf16x8*)(w1p + ks * 32);
      }
      float b0 = qkv_b[oc0], b1 = qkv_b[oc1];
      f32x4 acc0 = (f32x4){b0, b0, b0, b0};
      f32x4 acc1 = (f32x4){b1, b1, b1, b1};
      const unsigned short* a0p = &xb[(mt0 * 16 + ln) * 200 + lq * 8];
      const unsigned short* a1p = &xb[(mt1 * 16 + ln) * 200 + lq * 8];
#pragma unroll
      for (int ks = 0; ks < 6; ++ks) {
        bf16x8 a0 = *(const bf16x8*)(a0p + ks * 32);
        bf16x8 a1 = *(const bf16x8*)(a1p + ks * 32);
        acc0 = MFMA16(a0, w0[ks], acc0);
        acc1 = MFMA16(a1, w1[ks], acc1);
      }
      // epilogue: route tile to Q (scaled) / K / V^T LDS. C-layout:
      // row = mt*16 + lq*4 + r, col(within head) = (nt&1)*16 + ln
      {
        int which = nt0 >> 1, db = (nt0 & 1) * 16 + ln, row0 = mt0 * 16 + lq * 4;
        if (which == 0) {
#pragma unroll
          for (int r = 0; r < 4; ++r) Qs[(row0 + r) * 40 + db] = f2bf(acc0[r] * scale);
        } else if (which == 1) {
#pragma unroll
          for (int r = 0; r < 4; ++r) Ks[(row0 + r) * 40 + db] = f2bf(acc0[r]);
        } else {
          unsigned int lo = cvt_pk_bf16(acc0[0], acc0[1]);
          unsigned int hi = cvt_pk_bf16(acc0[2], acc0[3]);
          *(uint2*)(&Vts[db * 72 + row0]) = make_uint2(lo, hi);
        }
      }
      {
        int which = nt1 >> 1, db = (nt1 & 1) * 16 + ln, row0 = mt1 * 16 + lq * 4;
        if (which == 0) {
#pragma unroll
          for (int r = 0; r < 4; ++r) Qs[(row0 + r) * 40 + db] = f2bf(acc1[r] * scale);
        } else if (which == 1) {
#pragma unroll
          for (int r = 0; r < 4; ++r) Ks[(row0 + r) * 40 + db] = f2bf(acc1[r]);
        } else {
          unsigned int lo = cvt_pk_bf16(acc1[0], acc1[1]);
          unsigned int hi = cvt_pk_bf16(acc1[2], acc1[3]);
          *(uint2*)(&Vts[db * 72 + row0]) = make_uint2(lo, hi);
        }
      }
    }
    __syncthreads();

    // ---------------- attention, swapped operands. Wave owns q-block wv.
    {
      // S^T = K Q^T : A = K rows (token = nt*16+ln), B = Q cols (q = wv*16+ln)
      bf16x8 qf = *(const bf16x8*)&Qs[(wv * 16 + ln) * 40 + lq * 8];
      f32x4 sv[4];
#pragma unroll
      for (int nt = 0; nt < 4; ++nt) {
        bf16x8 kf = *(const bf16x8*)&Ks[(nt * 16 + ln) * 40 + lq * 8];
        sv[nt] = MFMA16(kf, qf, ((f32x4){0.f, 0.f, 0.f, 0.f}));
      }
      // lane holds S^T[k = nt*16+lq*4+r][q = wv*16+ln]; add bias+mask
      float tt[4][4];
#pragma unroll
      for (int nt = 0; nt < 4; ++nt) {
        float2 f01 = __half22float2(*(const __half2*)&bmu[nt].x);
        float2 f23 = __half22float2(*(const __half2*)&bmu[nt].y);
        tt[nt][0] = sv[nt][0] + f01.x;
        tt[nt][1] = sv[nt][1] + f01.y;
        tt[nt][2] = sv[nt][2] + f23.x;
        tt[nt][3] = sv[nt][3] + f23.y;
      }
      // softmax over k: 16 in-lane values + reduce across lq (lane bits 4,5)
      float m = tt[0][0];
#pragma unroll
      for (int nt = 0; nt < 4; ++nt)
#pragma unroll
        for (int r = 0; r < 4; ++r) m = fmaxf(m, tt[nt][r]);
      m = fmaxf(m, __shfl_xor(m, 16, 64));
      m = fmaxf(m, __shfl_xor(m, 32, 64));
      float sum = 0.f;
#pragma unroll
      for (int nt = 0; nt < 4; ++nt)
#pragma unroll
        for (int r = 0; r < 4; ++r) {
          float e = __expf(tt[nt][r] - m);
          tt[nt][r] = e;
          sum += e;
        }
      sum += __shfl_xor(sum, 16, 64);
      sum += __shfl_xor(sum, 32, 64);
      float pinv = 1.f / sum;

      // pack P^T to bf16 pairs: pk[nt][p] = (k=nt*16+lq*4+2p, +1)
      unsigned int pk[4][2];
#pragma unroll
      for (int nt = 0; nt < 4; ++nt) {
        pk[nt][0] = cvt_pk_bf16(tt[nt][0], tt[nt][1]);
        pk[nt][1] = cvt_pk_bf16(tt[nt][2], tt[nt][3]);
      }
      // redistribute to PV B-frag words: word(kb,w) = P^T[k=kb*32+lq*8+2w..+1][q]
      // source: lane lq_s=(lq&1)*2+(w>>1), value pk[2kb + (lq>>1)][w&1]
      union U8 { unsigned int u[4]; bf16x8 v; };
      U8 pb0, pb1;
#pragma unroll
      for (int w = 0; w < 4; ++w) {
        int src = (w & 2) ? sB : sA;
        int a0 = __shfl((int)pk[0][w & 1], src, 64);
        int a1 = __shfl((int)pk[1][w & 1], src, 64);
        int b0 = __shfl((int)pk[2][w & 1], src, 64);
        int b1 = __shfl((int)pk[3][w & 1], src, 64);
        pb0.u[w] = (unsigned int)(hiSel ? a1 : a0);
        pb1.u[w] = (unsigned int)(hiSel ? b1 : b0);
      }
      // O^T = V^T P^T : A = V^T (d = db*16+ln), B = P^T. C: d = db*16+lq*4+r
      f32x4 o[2];
#pragma unroll
      for (int db = 0; db < 2; ++db) {
        bf16x8 v0 = *(const bf16x8*)&Vts[(db * 16 + ln) * 72 + lq * 8];
        bf16x8 v1 = *(const bf16x8*)&Vts[(db * 16 + ln) * 72 + 32 + lq * 8];
        f32x4 acc = (f32x4){0.f, 0.f, 0.f, 0.f};
        acc = MFMA16(v0, pb0.v, acc);
        acc = MFMA16(v1, pb1.v, acc);
        o[db] = acc;
      }
      // normalize + pack O^T, redistribute to proj A-frag (same lq exchange)
      unsigned int pkO[2][2];
#pragma unroll
      for (int db = 0; db < 2; ++db) {
        pkO[db][0] = cvt_pk_bf16(o[db][0] * pinv, o[db][1] * pinv);
        pkO[db][1] = cvt_pk_bf16(o[db][2] * pinv, o[db][3] * pinv);
      }
      U8 oa;
#pragma unroll
      for (int w = 0; w < 4; ++w) {
        int src = (w & 2) ? sB : sA;
        int a0 = __shfl((int)pkO[0][w & 1], src, 64);
        int a1 = __shfl((int)pkO[1][w & 1], src, 64);
        oa.u[w] = (unsigned int)(hiSel ? a1 : a0);
      }
      // partial proj: A = O rows (q = wv*16+ln, d = lq*8..+7), K=32 slice
#pragma unroll
      for (int nti = 0; nti < 12; ++nti) {
        bf16x8 w = *(const bf16x8*)(proj_wb + (size_t)(nti * 16 + ln) * DIMC + h * 32 + lq * 8);
        pacc[nti] = MFMA16(oa.v, w, pacc[nti]);
      }
    }
    __syncthreads();  // Qs/Ks/Vts reused next head
  }

  // ---------------- store output (fp32): wave's q-rows, all 192 cols
  {
    float* outp = out + (size_t)b * (NTOK * DIMC);
#pragma unroll
    for (int nti = 0; nti < 12; ++nti) {
      int col = nti * 16 + ln;
#pragma unroll
      for (int r = 0; r < 4; ++r) {
        int row = wv * 16 + lq * 4 + r;
        if (row < NTOK) outp[row * DIMC + col] = pacc[nti][r];
      }
    }
  }
}

extern "C" void kernel_launch(void* const* d_in, const int* in_sizes, int n_in,
                              void* d_out, int out_size, void* d_ws, size_t ws_size,
                              hipStream_t stream) {
  const float* x = (const float*)d_in[0];
  const float* mask = (const float*)d_in[1];
  const float* qkv_w = (const float*)d_in[2];
  const float* qkv_b = (const float*)d_in[3];
  const float* proj_w = (const float*)d_in[4];
  const float* proj_b = (const float*)d_in[5];
  const float* bias_table = (const float*)d_in[6];
  const int* rel_idx = (const int*)d_in[7];

  unsigned short* qkv_wb = (unsigned short*)d_ws;                 // 576*192 bf16
  unsigned short* proj_wb = qkv_wb + 576 * 192;                   // 192*192 bf16
  __half* bmT = (__half*)(proj_wb + 192 * 192);                   // 64*6*4096 fp16

  prep_kernel<<<6144, 256, 0, stream>>>(qkv_w, proj_w, bias_table, rel_idx,
                                        mask, qkv_wb, proj_wb, bmT);
  winattn_kernel<<<4096, 256, 0, stream>>>(x, qkv_b, proj_b,
                                           qkv_wb, proj_wb, bmT,
                                           (float*)d_out);
}

// Round 2
// 528.275 us; speedup vs baseline: 1.1878x; 1.1878x over previous
//
#include <hip/hip_runtime.h>
#include <hip/hip_fp16.h>

// WindowAttention fused kernel for MI355X (gfx950).
// B=4096 windows, N=49 tokens (pad 64), C=192, H=6, hd=32.
// V3: all-heads QKV in one phase. x hoisted to registers (24 bf16x8/lane),
// each qkv weight loaded exactly once per block (was 4x redundant per head).
// Q/K/V^T for ALL heads parked in LDS (78.8 KB pool, xb aliased over Qall)
// -> head loop has ZERO LDS writes -> zero barriers inside it (3/block total,
// was 13). Attention/softmax/PV/proj = V2's verified lane-local pipeline.

typedef short bf16x8 __attribute__((ext_vector_type(8)));
typedef float f32x4 __attribute__((ext_vector_type(4)));

#define MFMA16(a, b, c) __builtin_amdgcn_mfma_f32_16x16x32_bf16((a), (b), (c), 0, 0, 0)

#define DIMC 192
#define NTOK 49

// round-to-nearest-even fp32 -> bf16
__device__ __forceinline__ unsigned short f2bf(float f) {
  unsigned int u = __float_as_uint(f);
  u += 0x7fffu + ((u >> 16) & 1u);
  return (unsigned short)(u >> 16);
}

// packed fp32x2 -> bf16x2 (RNE), single VALU op
__device__ __forceinline__ unsigned int cvt_pk_bf16(float lo, float hi) {
  unsigned int r;
  asm("v_cvt_pk_bf16_f32 %0, %1, %2" : "=v"(r) : "v"(lo), "v"(hi));
  return r;
}

// prep: bf16 weights + combined (bias+mask) fp16 table, fragment-permuted:
// bm[widx][h] tile of 4096 halfs, offset = ((nt*4 + lq)*64 + q)*4 + r,
// value = bias[h][q][k] + mask[widx][q][k], k = nt*16 + lq*4 + r.
// k >= 49 -> -30000 (masked keys), q >= 49 -> 0 (rows discarded).
__global__ void prep_kernel(const float* __restrict__ qkv_w,
                            const float* __restrict__ proj_w,
                            const float* __restrict__ bias_table,
                            const int* __restrict__ rel_idx,
                            const float* __restrict__ mask,
                            unsigned short* __restrict__ qkv_wb,
                            unsigned short* __restrict__ proj_wb,
                            __half* __restrict__ bmT) {
  int i = blockIdx.x * 256 + threadIdx.x;
  if (i < 576 * 192) qkv_wb[i] = f2bf(qkv_w[i]);
  if (i < 192 * 192) proj_wb[i] = f2bf(proj_w[i]);
  {
    int r = i & 3;
    int q = (i >> 2) & 63;
    int lq = (i >> 8) & 3;
    int nt = (i >> 10) & 3;
    int hw = i >> 12;          // widx*6 + h
    int h = hw % 6;
    int widx = hw / 6;
    int k = nt * 16 + lq * 4 + r;
    float v;
    if (k >= NTOK) v = -30000.f;
    else if (q >= NTOK) v = 0.f;
    else v = bias_table[rel_idx[q * NTOK + k] * 6 + h] +
             mask[(size_t)widx * (NTOK * NTOK) + q * NTOK + k];
    bmT[i] = __float2half(v);
  }
}

__global__ __launch_bounds__(256, 2) void winattn_kernel(
    const float* __restrict__ x,
    const float* __restrict__ qkv_b,
    const float* __restrict__ proj_b,
    const unsigned short* __restrict__ qkv_wb,
    const unsigned short* __restrict__ proj_wb,
    const __half* __restrict__ bmT,
    float* __restrict__ out) {
  // LDS pool: 78,848 B -> 2 blocks/CU. xb (transient) aliases Qall.
  __shared__ unsigned short pool[39424];
  unsigned short* xb   = pool;            // [64][200] bf16 x, dead after reg-load
  unsigned short* Qall = pool;            // [64 tok][200], cols 0..191 (scaled Q)
  unsigned short* Kall = pool + 12800;    // [64 tok][200], cols 0..191
  unsigned short* Vta  = pool + 25600;    // [192 d][72 tok]  (V^T, all heads)

  const int tid = threadIdx.x;
  const int b = blockIdx.x;
  const int widx = b & 63;
  const int lane = tid & 63;
  const int wv = tid >> 6;          // wave 0..3
  const int lq = lane >> 4;         // quad 0..3
  const int ln = lane & 15;

  // ---------------- stage x (bf16, zero rows >= 49)
  {
    const float4* xp = (const float4*)(x + (size_t)b * (NTOK * DIMC));
    for (int i = tid; i < NTOK * DIMC / 4; i += 256) {
      float4 v = xp[i];
      int fl = i * 4;
      int r = fl / DIMC;
      int c = fl - r * DIMC;
      unsigned int lo = (unsigned int)f2bf(v.x) | ((unsigned int)f2bf(v.y) << 16);
      unsigned int hi = (unsigned int)f2bf(v.z) | ((unsigned int)f2bf(v.w) << 16);
      *(uint2*)(&xb[r * 200 + c]) = make_uint2(lo, hi);
    }
    for (int i = tid; i < 15 * 200 / 2; i += 256)
      ((unsigned int*)(&xb[49 * 200]))[i] = 0u;
  }
  __syncthreads();

  // ---------------- hoist all of x into registers as MFMA A-frags.
  // af[mt][ks]: rows mt*16+ln, k = ks*32 + lq*8 .. +7  (24 bf16x8 = 96 VGPR)
  bf16x8 af[4][6];
#pragma unroll
  for (int mt = 0; mt < 4; ++mt)
#pragma unroll
    for (int ks = 0; ks < 6; ++ks)
      af[mt][ks] = *(const bf16x8*)&xb[(mt * 16 + ln) * 200 + ks * 32 + lq * 8];
  __syncthreads();  // xb dead; its LDS becomes Qall

  const float scale = 0.17677669529663687f;  // 1/sqrt(32)

  // ---------------- QKV for ALL heads: 36 col-tiles, wave owns 9 complete
  // columns (all 4 m-tiles each) -> every weight fetched once per block.
  for (int i = 0; i < 9; ++i) {
    int nt = wv * 9 + i;
    int c = nt * 16 + ln;                         // global out col 0..575
    const unsigned short* wp = qkv_wb + (size_t)c * DIMC + lq * 8;
    bf16x8 wf[6];
#pragma unroll
    for (int ks = 0; ks < 6; ++ks) wf[ks] = *(const bf16x8*)(wp + ks * 32);
    float bv = qkv_b[c];
    f32x4 a0 = (f32x4){bv, bv, bv, bv};
    f32x4 a1 = a0, a2 = a0, a3 = a0;
#pragma unroll
    for (int ks = 0; ks < 6; ++ks) {
      a0 = MFMA16(af[0][ks], wf[ks], a0);
      a1 = MFMA16(af[1][ks], wf[ks], a1);
      a2 = MFMA16(af[2][ks], wf[ks], a2);
      a3 = MFMA16(af[3][ks], wf[ks], a3);
    }
    f32x4 acc[4] = {a0, a1, a2, a3};
    // C-layout: row(token) = mt*16 + lq*4 + r, col = c (lane ln)
    int which = nt / 12;                          // 0=Q 1=K 2=V (tile-uniform)
    int colq = c - which * 192;                   // col within 192
    if (which == 0) {
#pragma unroll
      for (int mt = 0; mt < 4; ++mt) {
        int row0 = mt * 16 + lq * 4;
#pragma unroll
        for (int r = 0; r < 4; ++r)
          Qall[(row0 + r) * 200 + colq] = f2bf(acc[mt][r] * scale);
      }
    } else if (which == 1) {
#pragma unroll
      for (int mt = 0; mt < 4; ++mt) {
        int row0 = mt * 16 + lq * 4;
#pragma unroll
        for (int r = 0; r < 4; ++r)
          Kall[(row0 + r) * 200 + colq] = f2bf(acc[mt][r]);
      }
    } else {
#pragma unroll
      for (int mt = 0; mt < 4; ++mt) {
        int row0 = mt * 16 + lq * 4;
        unsigned int lo = cvt_pk_bf16(acc[mt][0], acc[mt][1]);
        unsigned int hi = cvt_pk_bf16(acc[mt][2], acc[mt][3]);
        *(uint2*)(&Vta[colq * 72 + row0]) = make_uint2(lo, hi);
      }
    }
  }
  __syncthreads();  // Q/K/V^T (all heads) ready; NO more barriers below.

  // persistent proj accumulators: wave owns q-rows [wv*16, wv*16+16), all 192 cols
  f32x4 pacc[12];
#pragma unroll
  for (int nti = 0; nti < 12; ++nti) {
    float pbv = proj_b[nti * 16 + ln];
    pacc[nti] = (f32x4){pbv, pbv, pbv, pbv};
  }

  const __half* bmp = bmT + (size_t)widx * 6 * 4096;
  // cross-lq redistribution source lanes (same ln, lq_s = (lq&1)*2 + {0,1})
  const int sA = ((lq & 1) << 5) | ln;
  const int sB = sA + 16;
  const int hiSel = lq >> 1;

  for (int h = 0; h < 6; ++h) {
    // bias+mask fragments: lane covers k = nt*16+lq*4+{0..3}, q = wv*16+ln
    uint2 bmu[4];
    {
      const __half* bmh = bmp + (size_t)h * 4096;
#pragma unroll
      for (int nt = 0; nt < 4; ++nt)
        bmu[nt] = *(const uint2*)(bmh + ((nt * 4 + lq) * 64 + wv * 16 + ln) * 4);
    }

    // S^T = K Q^T : A = K rows (token = nt*16+ln), B = Q cols (q = wv*16+ln)
    bf16x8 qf = *(const bf16x8*)&Qall[(wv * 16 + ln) * 200 + h * 32 + lq * 8];
    f32x4 sv[4];
#pragma unroll
    for (int nt = 0; nt < 4; ++nt) {
      bf16x8 kf = *(const bf16x8*)&Kall[(nt * 16 + ln) * 200 + h * 32 + lq * 8];
      sv[nt] = MFMA16(kf, qf, ((f32x4){0.f, 0.f, 0.f, 0.f}));
    }
    // lane holds S^T[k = nt*16+lq*4+r][q = wv*16+ln]; add bias+mask
    float tt[4][4];
#pragma unroll
    for (int nt = 0; nt < 4; ++nt) {
      float2 f01 = __half22float2(*(const __half2*)&bmu[nt].x);
      float2 f23 = __half22float2(*(const __half2*)&bmu[nt].y);
      tt[nt][0] = sv[nt][0] + f01.x;
      tt[nt][1] = sv[nt][1] + f01.y;
      tt[nt][2] = sv[nt][2] + f23.x;
      tt[nt][3] = sv[nt][3] + f23.y;
    }
    // softmax over k: 16 in-lane values + reduce across lq (lane bits 4,5)
    float m = tt[0][0];
#pragma unroll
    for (int nt = 0; nt < 4; ++nt)
#pragma unroll
      for (int r = 0; r < 4; ++r) m = fmaxf(m, tt[nt][r]);
    m = fmaxf(m, __shfl_xor(m, 16, 64));
    m = fmaxf(m, __shfl_xor(m, 32, 64));
    float sum = 0.f;
#pragma unroll
    for (int nt = 0; nt < 4; ++nt)
#pragma unroll
      for (int r = 0; r < 4; ++r) {
        float e = __expf(tt[nt][r] - m);
        tt[nt][r] = e;
        sum += e;
      }
    sum += __shfl_xor(sum, 16, 64);
    sum += __shfl_xor(sum, 32, 64);
    float pinv = 1.f / sum;

    // pack P^T to bf16 pairs: pk[nt][p] = (k=nt*16+lq*4+2p, +1)
    unsigned int pk[4][2];
#pragma unroll
    for (int nt = 0; nt < 4; ++nt) {
      pk[nt][0] = cvt_pk_bf16(tt[nt][0], tt[nt][1]);
      pk[nt][1] = cvt_pk_bf16(tt[nt][2], tt[nt][3]);
    }
    // redistribute to PV B-frag words: word(kb,w) = P^T[k=kb*32+lq*8+2w..+1][q]
    union U8 { unsigned int u[4]; bf16x8 v; };
    U8 pb0, pb1;
#pragma unroll
    for (int w = 0; w < 4; ++w) {
      int src = (w & 2) ? sB : sA;
      int a0 = __shfl((int)pk[0][w & 1], src, 64);
      int a1 = __shfl((int)pk[1][w & 1], src, 64);
      int b0 = __shfl((int)pk[2][w & 1], src, 64);
      int b1 = __shfl((int)pk[3][w & 1], src, 64);
      pb0.u[w] = (unsigned int)(hiSel ? a1 : a0);
      pb1.u[w] = (unsigned int)(hiSel ? b1 : b0);
    }
    // O^T = V^T P^T : A = V^T (d = h*32 + db*16+ln), B = P^T. C: d = db*16+lq*4+r
    f32x4 o[2];
#pragma unroll
    for (int db = 0; db < 2; ++db) {
      bf16x8 v0 = *(const bf16x8*)&Vta[(h * 32 + db * 16 + ln) * 72 + lq * 8];
      bf16x8 v1 = *(const bf16x8*)&Vta[(h * 32 + db * 16 + ln) * 72 + 32 + lq * 8];
      f32x4 acc = (f32x4){0.f, 0.f, 0.f, 0.f};
      acc = MFMA16(v0, pb0.v, acc);
      acc = MFMA16(v1, pb1.v, acc);
      o[db] = acc;
    }
    // normalize + pack O^T, redistribute to proj A-frag (same lq exchange)
    unsigned int pkO[2][2];
#pragma unroll
    for (int db = 0; db < 2; ++db) {
      pkO[db][0] = cvt_pk_bf16(o[db][0] * pinv, o[db][1] * pinv);
      pkO[db][1] = cvt_pk_bf16(o[db][2] * pinv, o[db][3] * pinv);
    }
    U8 oa;
#pragma unroll
    for (int w = 0; w < 4; ++w) {
      int src = (w & 2) ? sB : sA;
      int a0 = __shfl((int)pkO[0][w & 1], src, 64);
      int a1 = __shfl((int)pkO[1][w & 1], src, 64);
      oa.u[w] = (unsigned int)(hiSel ? a1 : a0);
    }
    // partial proj: A = O rows (q = wv*16+ln, d = lq*8..+7), K=32 slice
#pragma unroll
    for (int nti = 0; nti < 12; ++nti) {
      bf16x8 w = *(const bf16x8*)(proj_wb + (size_t)(nti * 16 + ln) * DIMC + h * 32 + lq * 8);
      pacc[nti] = MFMA16(oa.v, w, pacc[nti]);
    }
  }

  // ---------------- store output (fp32): wave's q-rows, all 192 cols
  {
    float* outp = out + (size_t)b * (NTOK * DIMC);
#pragma unroll
    for (int nti = 0; nti < 12; ++nti) {
      int col = nti * 16 + ln;
#pragma unroll
      for (int r = 0; r < 4; ++r) {
        int row = wv * 16 + lq * 4 + r;
        if (row < NTOK) outp[row * DIMC + col] = pacc[nti][r];
      }
    }
  }
}

extern "C" void kernel_launch(void* const* d_in, const int* in_sizes, int n_in,
                              void* d_out, int out_size, void* d_ws, size_t ws_size,
                              hipStream_t stream) {
  const float* x = (const float*)d_in[0];
  const float* mask = (const float*)d_in[1];
  const float* qkv_w = (const float*)d_in[2];
  const float* qkv_b = (const float*)d_in[3];
  const float* proj_w = (const float*)d_in[4];
  const float* proj_b = (const float*)d_in[5];
  const float* bias_table = (const float*)d_in[6];
  const int* rel_idx = (const int*)d_in[7];

  unsigned short* qkv_wb = (unsigned short*)d_ws;                 // 576*192 bf16
  unsigned short* proj_wb = qkv_wb + 576 * 192;                   // 192*192 bf16
  __half* bmT = (__half*)(proj_wb + 192 * 192);                   // 64*6*4096 fp16

  prep_kernel<<<6144, 256, 0, stream>>>(qkv_w, proj_w, bias_table, rel_idx,
                                        mask, qkv_wb, proj_wb, bmT);
  winattn_kernel<<<4096, 256, 0, stream>>>(x, qkv_b, proj_b,
                                           qkv_wb, proj_wb, bmT,
                                           (float*)d_out);
}